// Round 3
// baseline (984.860 us; speedup 1.0000x reference)
//
#include <hip/hip_runtime.h>

#define NN 100000
#define NE 1600000
#define NG 1024
#define NODE_IN 163
#define SLOPE 0.01f
#define NBUK 391      // ceil(100000/256)
#define BUKSH 8       // 256 nodes per bucket

// Phase A: histogram of dst>>8 into bcnt[NBUK] via LDS
__global__ void k_bcount(const int* __restrict__ dst, int* __restrict__ bcnt, int E) {
  __shared__ int h[NBUK];
  for (int i = threadIdx.x; i < NBUK; i += 256) h[i] = 0;
  __syncthreads();
  for (int i = blockIdx.x * 256 + threadIdx.x; i < E; i += gridDim.x * 256)
    atomicAdd(&h[dst[i] >> BUKSH], 1);
  __syncthreads();
  for (int i = threadIdx.x; i < NBUK; i += 256) if (h[i]) atomicAdd(&bcnt[i], h[i]);
}

// Phase B: exclusive scan of bucket counts -> boffs, bcur
__global__ void k_scan_buckets(const int* __restrict__ bcnt, int* __restrict__ boffs,
                               int* __restrict__ bcur, int E) {
  __shared__ int s[512];
  int tid = threadIdx.x;
  int v = (tid < NBUK) ? bcnt[tid] : 0;
  s[tid] = v;
  __syncthreads();
  for (int off = 1; off < 512; off <<= 1) {
    int t = (tid >= off) ? s[tid - off] : 0;
    __syncthreads();
    s[tid] += t;
    __syncthreads();
  }
  if (tid < NBUK) { boffs[tid] = s[tid] - v; bcur[tid] = s[tid] - v; }
  if (tid == 0) boffs[NBUK] = E;
}

// Phase C: append packed edges to bucket regions (writes cluster per bucket)
__global__ void k_bfill(const int* __restrict__ src, const int* __restrict__ dst,
                        int* __restrict__ bcur, unsigned* __restrict__ bedge, int E) {
  int i = blockIdx.x * 256 + threadIdx.x;
  if (i < E) {
    int d = dst[i];
    int pos = atomicAdd(&bcur[d >> BUKSH], 1);
    bedge[pos] = (unsigned)src[i] | ((unsigned)(d & 255) << 17);
  }
}

// Phase D: per-bucket local count/scan/scatter -> csr, offs, dis (XCD-local writes)
__global__ void k_b2csr(const unsigned* __restrict__ bedge, const int* __restrict__ boffs,
                        int* __restrict__ offs, float* __restrict__ dis,
                        int* __restrict__ csr, int N) {
  __shared__ int lcnt[256];
  __shared__ int s[256];
  __shared__ int lcur[256];
  int b = blockIdx.x, tid = threadIdx.x;
  int beg = boffs[b], end = boffs[b + 1];
  lcnt[tid] = 0;
  __syncthreads();
  for (int e = beg + tid; e < end; e += 256) atomicAdd(&lcnt[bedge[e] >> 17], 1);
  __syncthreads();
  int v = lcnt[tid];
  s[tid] = v;
  __syncthreads();
  for (int off = 1; off < 256; off <<= 1) {
    int t = (tid >= off) ? s[tid - off] : 0;
    __syncthreads();
    s[tid] += t;
    __syncthreads();
  }
  int o = s[tid] - v;
  int node = (b << BUKSH) + tid;
  if (node <= N) offs[node] = beg + o;
  if (node < N) dis[node] = rsqrtf((float)(v + 1));
  lcur[tid] = o;
  __syncthreads();
  for (int e = beg + tid; e < end; e += 256) {
    unsigned w = bedge[e];
    int p = atomicAdd(&lcur[w >> 17], 1);
    csr[beg + p] = (int)(w & 0x1FFFFu);
  }
}

// Y[N,64] = (X[N,K] @ W[K,64]) * dis[row]
// lane = row (64 rows/block), wave = 16-col slice. X staged in LDS with coprime
// pitch (conflict-free b32 reads); W read via uniform scalar loads (no LDS).
template<int K, int PITCH>
__launch_bounds__(256)
__global__ void k_gemm(const float* __restrict__ X, const float* __restrict__ W,
                       const float* __restrict__ disv, float* __restrict__ Y, int N) {
  __shared__ float sX[64 * PITCH];
  const int tid = threadIdx.x;
  const int lane = tid & 63;
  const int c0u = __builtin_amdgcn_readfirstlane((tid >> 6) * 16);
  const int tile = blockIdx.x * 64;

  if (K == NODE_IN) {
    // flat contiguous copy; 64*163 and 32*163 are both /4; base 16B-aligned
    int rows = min(64, N - tile);
    int nf4 = (rows * K) >> 2;
    const float4* src4 = (const float4*)(X + (size_t)tile * K);
    float4* dst4 = (float4*)sX;
    for (int i = tid; i < nf4; i += 256) dst4[i] = src4[i];
  } else {
    // K==64, PITCH==65: read own row float4s, write 4x b32 (banks (lane+k)%32, free)
    const int w = tid >> 6;
    const float* xr = X + (size_t)(tile + lane) * 64 + w * 16;
    #pragma unroll
    for (int m = 0; m < 4; ++m) {
      float4 t = *(const float4*)(xr + m * 4);
      int base = lane * PITCH + w * 16 + m * 4;
      sX[base + 0] = t.x; sX[base + 1] = t.y; sX[base + 2] = t.z; sX[base + 3] = t.w;
    }
  }
  __syncthreads();

  float acc[16] = {};
  #pragma unroll 4
  for (int k = 0; k < K; ++k) {
    float xv = sX[lane * PITCH + k];
    const float4* wp = (const float4*)(W + (size_t)k * 64 + c0u);
    float4 w0 = wp[0], w1 = wp[1], w2 = wp[2], w3 = wp[3];
    acc[0]  += xv * w0.x; acc[1]  += xv * w0.y; acc[2]  += xv * w0.z; acc[3]  += xv * w0.w;
    acc[4]  += xv * w1.x; acc[5]  += xv * w1.y; acc[6]  += xv * w1.z; acc[7]  += xv * w1.w;
    acc[8]  += xv * w2.x; acc[9]  += xv * w2.y; acc[10] += xv * w2.z; acc[11] += xv * w2.w;
    acc[12] += xv * w3.x; acc[13] += xv * w3.y; acc[14] += xv * w3.z; acc[15] += xv * w3.w;
  }

  int row = tile + lane;
  if (row < N) {
    float d = disv[row];
    float* yp = Y + (size_t)row * 64 + c0u;
    #pragma unroll
    for (int j = 0; j < 4; ++j) {
      float4 o = make_float4(acc[j*4+0]*d, acc[j*4+1]*d, acc[j*4+2]*d, acc[j*4+3]*d);
      *(float4*)(yp + j * 4) = o;
    }
  }
}

// One wave per node: Hout[i] = lrelu( (Hps[i] + sum_{e->i} Hps[src]) * dis[i] + b )
__launch_bounds__(256)
__global__ void k_agg(const float* __restrict__ Hps, const int* __restrict__ offs,
                      const int* __restrict__ csr, const float* __restrict__ dis,
                      const float* __restrict__ bias, float* __restrict__ Hout, int N) {
  int node = blockIdx.x * 4 + (threadIdx.x >> 6);
  if (node >= N) return;
  int lane = threadIdx.x & 63;
  int beg = offs[node], end = offs[node + 1];
  float acc = Hps[(size_t)node * 64 + lane];
  int e = beg;
  for (; e + 4 <= end; e += 4) {
    int s0 = csr[e], s1 = csr[e + 1], s2 = csr[e + 2], s3 = csr[e + 3];
    acc += Hps[(size_t)s0 * 64 + lane];
    acc += Hps[(size_t)s1 * 64 + lane];
    acc += Hps[(size_t)s2 * 64 + lane];
    acc += Hps[(size_t)s3 * 64 + lane];
  }
  for (; e < end; ++e) acc += Hps[(size_t)csr[e] * 64 + lane];
  acc = acc * dis[node] + bias[lane];
  Hout[(size_t)node * 64 + lane] = (acc > 0.f) ? acc : SLOPE * acc;
}

// One wave per graph: mean-pool + fc1 + lrelu + fc2
__launch_bounds__(64)
__global__ void k_pool(const float* __restrict__ H, const int* __restrict__ batch,
                       const float* __restrict__ f1W, const float* __restrict__ f1b,
                       const float* __restrict__ f2W, const float* __restrict__ f2b,
                       float* __restrict__ out, int N) {
  int g = blockIdx.x;
  int lane = threadIdx.x;
  int lo = 0, hi = N;
  while (lo < hi) { int m = (lo + hi) >> 1; if (batch[m] < g) lo = m + 1; else hi = m; }
  int beg = lo;
  hi = N;
  while (lo < hi) { int m = (lo + hi) >> 1; if (batch[m] < g + 1) lo = m + 1; else hi = m; }
  int end = lo;
  float acc = 0.f;
  for (int r = beg; r < end; ++r) acc += H[(size_t)r * 64 + lane];
  float c = (float)(end - beg);
  acc /= (c < 1.f ? 1.f : c);
  __shared__ float p[64];
  p[lane] = acc;
  __syncthreads();
  float q = f1b[lane];
  #pragma unroll
  for (int k = 0; k < 64; ++k) q += p[k] * f1W[k * 64 + lane];
  q = (q > 0.f) ? q : SLOPE * q;
  float v = q * f2W[lane];
  #pragma unroll
  for (int off = 32; off > 0; off >>= 1) v += __shfl_down(v, off, 64);
  if (lane == 0) out[g] = v + f2b[0];
}

extern "C" void kernel_launch(void* const* d_in, const int* in_sizes, int n_in,
                              void* d_out, int out_size, void* d_ws, size_t ws_size,
                              hipStream_t stream) {
  const float* x    = (const float*)d_in[0];
  const int*  eidx  = (const int*)d_in[1];
  const int*  batch = (const int*)d_in[2];
  const float* W0 = (const float*)d_in[3];
  const float* b0 = (const float*)d_in[4];
  const float* W1 = (const float*)d_in[5];
  const float* b1 = (const float*)d_in[6];
  const float* W2 = (const float*)d_in[7];
  const float* b2 = (const float*)d_in[8];
  const float* f1W = (const float*)d_in[9];
  const float* f1b = (const float*)d_in[10];
  const float* f2W = (const float*)d_in[11];
  const float* f2b = (const float*)d_in[12];
  float* out = (float*)d_out;

  const int N = NN, E = NE;
  const int* src  = eidx;
  const int* dstp = eidx + E;

  const size_t NPAD = 100096;   // rows padded so K=64 staging may over-read safely
  char* w = (char*)d_ws;
  float* bufA  = (float*)w; w += NPAD * 64 * 4;   // bedge aliases bufA (dead by gemm0)
  float* bufB  = (float*)w; w += NPAD * 64 * 4;
  int*   csr   = (int*)w;   w += (size_t)E * 4;
  int*   offs  = (int*)w;   w += (size_t)(N + 4) * 4;
  float* dis   = (float*)w; w += (size_t)N * 4;
  int*   bcnt  = (int*)w;   w += (NBUK + 1) * 4;
  int*   boffs = (int*)w;   w += (NBUK + 1) * 4;
  int*   bcur  = (int*)w;   w += (NBUK + 1) * 4;
  unsigned* bedge = (unsigned*)bufA;

  hipMemsetAsync(bcnt, 0, NBUK * 4, stream);
  k_bcount<<<512, 256, 0, stream>>>(dstp, bcnt, E);
  k_scan_buckets<<<1, 512, 0, stream>>>(bcnt, boffs, bcur, E);
  k_bfill<<<(E + 255) / 256, 256, 0, stream>>>(src, dstp, bcur, bedge, E);
  k_b2csr<<<NBUK, 256, 0, stream>>>(bedge, boffs, offs, dis, csr, N);

  const int GB = (N + 63) / 64;
  k_gemm<NODE_IN, NODE_IN><<<GB, 256, 0, stream>>>(x, W0, dis, bufA, N);
  k_agg<<<(N + 3) / 4, 256, 0, stream>>>(bufA, offs, csr, dis, b0, bufB, N);
  k_gemm<64, 65><<<GB, 256, 0, stream>>>(bufB, W1, dis, bufA, N);
  k_agg<<<(N + 3) / 4, 256, 0, stream>>>(bufA, offs, csr, dis, b1, bufB, N);
  k_gemm<64, 65><<<GB, 256, 0, stream>>>(bufB, W2, dis, bufA, N);
  k_agg<<<(N + 3) / 4, 256, 0, stream>>>(bufA, offs, csr, dis, b2, bufB, N);
  k_pool<<<NG, 64, 0, stream>>>(bufB, batch, f1W, f1b, f2W, f2b, out, N);
}

// Round 4
// 437.631 us; speedup vs baseline: 2.2504x; 2.2504x over previous
//
#include <hip/hip_runtime.h>

#define NN 100000
#define NE 1600000
#define NG 1024
#define NODE_IN 163
#define SLOPE 0.01f
#define NBUK 391      // ceil(100000/256)
#define BUKSH 8       // 256 nodes per bucket
#define EPB 8192      // edges per partition block
#define NBLK ((NE + EPB - 1) / EPB)   // 196

// Per-block privatized histogram over buckets (no global atomics).
__global__ void k_hist(const int* __restrict__ dst, int* __restrict__ bh, int E) {
  __shared__ int h[NBUK];
  for (int i = threadIdx.x; i < NBUK; i += 256) h[i] = 0;
  __syncthreads();
  int beg = blockIdx.x * EPB, end = min(E, beg + EPB);
  for (int e = beg + threadIdx.x; e < end; e += 256) atomicAdd(&h[dst[e] >> BUKSH], 1);
  __syncthreads();
  for (int i = threadIdx.x; i < NBUK; i += 256) bh[blockIdx.x * NBUK + i] = h[i];
}

// Per bucket: exclusive scan down the block axis (in place) + bucket total.
__global__ void k_bucket_scan(int* __restrict__ bh, int* __restrict__ btot) {
  __shared__ int s[256];
  int bucket = blockIdx.x, tid = threadIdx.x;
  int v = (tid < NBLK) ? bh[tid * NBUK + bucket] : 0;
  s[tid] = v;
  __syncthreads();
  for (int off = 1; off < 256; off <<= 1) {
    int t = (tid >= off) ? s[tid - off] : 0;
    __syncthreads();
    s[tid] += t;
    __syncthreads();
  }
  if (tid < NBLK) bh[tid * NBUK + bucket] = s[tid] - v;
  if (tid == 255) btot[bucket] = s[255];
}

__global__ void k_btot_scan(const int* __restrict__ btot, int* __restrict__ boffs, int E) {
  __shared__ int s[512];
  int tid = threadIdx.x;
  int v = (tid < NBUK) ? btot[tid] : 0;
  s[tid] = v;
  __syncthreads();
  for (int off = 1; off < 512; off <<= 1) {
    int t = (tid >= off) ? s[tid - off] : 0;
    __syncthreads();
    s[tid] += t;
    __syncthreads();
  }
  if (tid < NBUK) boffs[tid] = s[tid] - v;
  if (tid == 0) boffs[NBUK] = E;
}

// Scatter edges to bucket-grouped array; cursors live in LDS (no global atomics).
__global__ void k_scatter(const int* __restrict__ src, const int* __restrict__ dst,
                          const int* __restrict__ bh, const int* __restrict__ boffs,
                          unsigned* __restrict__ bedge, int E) {
  __shared__ int cur[NBUK];
  for (int i = threadIdx.x; i < NBUK; i += 256)
    cur[i] = boffs[i] + bh[blockIdx.x * NBUK + i];
  __syncthreads();
  int beg = blockIdx.x * EPB, end = min(E, beg + EPB);
  for (int e = beg + threadIdx.x; e < end; e += 256) {
    int d = dst[e];
    int pos = atomicAdd(&cur[d >> BUKSH], 1);
    bedge[pos] = (unsigned)src[e] | ((unsigned)(d & 255) << 17);
  }
}

// Per-bucket local count/scan/scatter -> csr, offs, dis
__global__ void k_b2csr(const unsigned* __restrict__ bedge, const int* __restrict__ boffs,
                        int* __restrict__ offs, float* __restrict__ dis,
                        int* __restrict__ csr, int N) {
  __shared__ int lcnt[256];
  __shared__ int s[256];
  __shared__ int lcur[256];
  int b = blockIdx.x, tid = threadIdx.x;
  int beg = boffs[b], end = boffs[b + 1];
  lcnt[tid] = 0;
  __syncthreads();
  for (int e = beg + tid; e < end; e += 256) atomicAdd(&lcnt[bedge[e] >> 17], 1);
  __syncthreads();
  int v = lcnt[tid];
  s[tid] = v;
  __syncthreads();
  for (int off = 1; off < 256; off <<= 1) {
    int t = (tid >= off) ? s[tid - off] : 0;
    __syncthreads();
    s[tid] += t;
    __syncthreads();
  }
  int o = s[tid] - v;
  int node = (b << BUKSH) + tid;
  if (node <= N) offs[node] = beg + o;
  if (node < N) dis[node] = rsqrtf((float)(v + 1));
  lcur[tid] = o;
  __syncthreads();
  for (int e = beg + tid; e < end; e += 256) {
    unsigned w = bedge[e];
    int p = atomicAdd(&lcur[w >> 17], 1);
    csr[beg + p] = (int)(w & 0x1FFFFu);
  }
}

// Y[N,64] = (X[N,K] @ W[K,64]) * dis[row]
template<int K, int PITCH>
__launch_bounds__(256)
__global__ void k_gemm(const float* __restrict__ X, const float* __restrict__ W,
                       const float* __restrict__ disv, float* __restrict__ Y, int N) {
  __shared__ float sX[64 * PITCH];
  const int tid = threadIdx.x;
  const int lane = tid & 63;
  const int c0u = __builtin_amdgcn_readfirstlane((tid >> 6) * 16);
  const int tile = blockIdx.x * 64;

  if (K == NODE_IN) {
    int rows = min(64, N - tile);
    int nf4 = (rows * K) >> 2;
    const float4* src4 = (const float4*)(X + (size_t)tile * K);
    float4* dst4 = (float4*)sX;
    for (int i = tid; i < nf4; i += 256) dst4[i] = src4[i];
  } else {
    const int w = tid >> 6;
    const float* xr = X + (size_t)(tile + lane) * 64 + w * 16;
    #pragma unroll
    for (int m = 0; m < 4; ++m) {
      float4 t = *(const float4*)(xr + m * 4);
      int base = lane * PITCH + w * 16 + m * 4;
      sX[base + 0] = t.x; sX[base + 1] = t.y; sX[base + 2] = t.z; sX[base + 3] = t.w;
    }
  }
  __syncthreads();

  float acc[16] = {};
  #pragma unroll 4
  for (int k = 0; k < K; ++k) {
    float xv = sX[lane * PITCH + k];
    const float4* wp = (const float4*)(W + (size_t)k * 64 + c0u);
    float4 w0 = wp[0], w1 = wp[1], w2 = wp[2], w3 = wp[3];
    acc[0]  += xv * w0.x; acc[1]  += xv * w0.y; acc[2]  += xv * w0.z; acc[3]  += xv * w0.w;
    acc[4]  += xv * w1.x; acc[5]  += xv * w1.y; acc[6]  += xv * w1.z; acc[7]  += xv * w1.w;
    acc[8]  += xv * w2.x; acc[9]  += xv * w2.y; acc[10] += xv * w2.z; acc[11] += xv * w2.w;
    acc[12] += xv * w3.x; acc[13] += xv * w3.y; acc[14] += xv * w3.z; acc[15] += xv * w3.w;
  }

  int row = tile + lane;
  if (row < N) {
    float d = disv[row];
    float* yp = Y + (size_t)row * 64 + c0u;
    #pragma unroll
    for (int j = 0; j < 4; ++j) {
      float4 o = make_float4(acc[j*4+0]*d, acc[j*4+1]*d, acc[j*4+2]*d, acc[j*4+3]*d);
      *(float4*)(yp + j * 4) = o;
    }
  }
}

// One wave per node: Hout[i] = lrelu( (Hps[i] + sum_{e->i} Hps[src]) * dis[i] + b )
__launch_bounds__(256)
__global__ void k_agg(const float* __restrict__ Hps, const int* __restrict__ offs,
                      const int* __restrict__ csr, const float* __restrict__ dis,
                      const float* __restrict__ bias, float* __restrict__ Hout, int N) {
  int node = blockIdx.x * 4 + (threadIdx.x >> 6);
  if (node >= N) return;
  int lane = threadIdx.x & 63;
  int beg = offs[node], end = offs[node + 1];
  float acc = Hps[(size_t)node * 64 + lane];
  int e = beg;
  for (; e + 4 <= end; e += 4) {
    int s0 = csr[e], s1 = csr[e + 1], s2 = csr[e + 2], s3 = csr[e + 3];
    acc += Hps[(size_t)s0 * 64 + lane];
    acc += Hps[(size_t)s1 * 64 + lane];
    acc += Hps[(size_t)s2 * 64 + lane];
    acc += Hps[(size_t)s3 * 64 + lane];
  }
  for (; e < end; ++e) acc += Hps[(size_t)csr[e] * 64 + lane];
  acc = acc * dis[node] + bias[lane];
  Hout[(size_t)node * 64 + lane] = (acc > 0.f) ? acc : SLOPE * acc;
}

// One wave per graph: mean-pool + fc1 + lrelu + fc2
__launch_bounds__(64)
__global__ void k_pool(const float* __restrict__ H, const int* __restrict__ batch,
                       const float* __restrict__ f1W, const float* __restrict__ f1b,
                       const float* __restrict__ f2W, const float* __restrict__ f2b,
                       float* __restrict__ out, int N) {
  int g = blockIdx.x;
  int lane = threadIdx.x;
  int lo = 0, hi = N;
  while (lo < hi) { int m = (lo + hi) >> 1; if (batch[m] < g) lo = m + 1; else hi = m; }
  int beg = lo;
  hi = N;
  while (lo < hi) { int m = (lo + hi) >> 1; if (batch[m] < g + 1) lo = m + 1; else hi = m; }
  int end = lo;
  float acc = 0.f;
  for (int r = beg; r < end; ++r) acc += H[(size_t)r * 64 + lane];
  float c = (float)(end - beg);
  acc /= (c < 1.f ? 1.f : c);
  __shared__ float p[64];
  p[lane] = acc;
  __syncthreads();
  float q = f1b[lane];
  #pragma unroll
  for (int k = 0; k < 64; ++k) q += p[k] * f1W[k * 64 + lane];
  q = (q > 0.f) ? q : SLOPE * q;
  float v = q * f2W[lane];
  #pragma unroll
  for (int off = 32; off > 0; off >>= 1) v += __shfl_down(v, off, 64);
  if (lane == 0) out[g] = v + f2b[0];
}

extern "C" void kernel_launch(void* const* d_in, const int* in_sizes, int n_in,
                              void* d_out, int out_size, void* d_ws, size_t ws_size,
                              hipStream_t stream) {
  const float* x    = (const float*)d_in[0];
  const int*  eidx  = (const int*)d_in[1];
  const int*  batch = (const int*)d_in[2];
  const float* W0 = (const float*)d_in[3];
  const float* b0 = (const float*)d_in[4];
  const float* W1 = (const float*)d_in[5];
  const float* b1 = (const float*)d_in[6];
  const float* W2 = (const float*)d_in[7];
  const float* b2 = (const float*)d_in[8];
  const float* f1W = (const float*)d_in[9];
  const float* f1b = (const float*)d_in[10];
  const float* f2W = (const float*)d_in[11];
  const float* f2b = (const float*)d_in[12];
  float* out = (float*)d_out;

  const int N = NN, E = NE;
  const int* src  = eidx;
  const int* dstp = eidx + E;

  const size_t NPAD = 100096;
  char* w = (char*)d_ws;
  float* bufA  = (float*)w; w += NPAD * 64 * 4;   // bedge aliases bufA (dead until gemm0)
  float* bufB  = (float*)w; w += NPAD * 64 * 4;
  int*   csr   = (int*)w;   w += (size_t)E * 4;
  int*   offs  = (int*)w;   w += (size_t)(N + 4) * 4;
  float* dis   = (float*)w; w += (size_t)N * 4;
  int*   bh    = (int*)w;   w += (size_t)NBLK * NBUK * 4;
  int*   btot  = (int*)w;   w += (NBUK + 1) * 4;
  int*   boffs = (int*)w;   w += (NBUK + 1) * 4;
  unsigned* bedge = (unsigned*)bufA;

  k_hist<<<NBLK, 256, 0, stream>>>(dstp, bh, E);
  k_bucket_scan<<<NBUK, 256, 0, stream>>>(bh, btot);
  k_btot_scan<<<1, 512, 0, stream>>>(btot, boffs, E);
  k_scatter<<<NBLK, 256, 0, stream>>>(src, dstp, bh, boffs, bedge, E);
  k_b2csr<<<NBUK, 256, 0, stream>>>(bedge, boffs, offs, dis, csr, N);

  const int GB = (N + 63) / 64;
  k_gemm<NODE_IN, NODE_IN><<<GB, 256, 0, stream>>>(x, W0, dis, bufA, N);
  k_agg<<<(N + 3) / 4, 256, 0, stream>>>(bufA, offs, csr, dis, b0, bufB, N);
  k_gemm<64, 65><<<GB, 256, 0, stream>>>(bufB, W1, dis, bufA, N);
  k_agg<<<(N + 3) / 4, 256, 0, stream>>>(bufA, offs, csr, dis, b1, bufB, N);
  k_gemm<64, 65><<<GB, 256, 0, stream>>>(bufB, W2, dis, bufA, N);
  k_agg<<<(N + 3) / 4, 256, 0, stream>>>(bufA, offs, csr, dis, b2, bufB, N);
  k_pool<<<NG, 64, 0, stream>>>(bufB, batch, f1W, f1b, f2W, f2b, out, N);
}